// Round 6
// baseline (12627.431 us; speedup 1.0000x reference)
//
#include <hip/hip_runtime.h>
#include <math.h>

#define NSTEP 4095   // T-1 sequence steps
#define EDIM  512
#define HDIM  1024
#define GDIM  4096   // 4*H
#define KDIM  1024   // 2E == H == 1024 for both GEMMs
#define CDIM  1221
#define SNWG  64     // scan workgroups
#define UNITS 16     // hidden units per scan WG (64 gate rows)

__device__ __forceinline__ float sigmoidf_(float v) {
    return 1.0f / (1.0f + __expf(-v));
}
__device__ __forceinline__ float tanhf_(float v) {
    v = fminf(fmaxf(v, -15.0f), 15.0f);      // avoid inf/inf NaN
    const float e2 = __expf(2.0f * v);
    return (e2 - 1.0f) / (e2 + 1.0f);
}

// ---------------------------------------------------------------------------
// GEMM1: xg[m][n] = sum_k A[m][k]*W_ih[n][k] + b_ih[n] + b_hh[n]
//   A[m][k] = emb[x[m]][k] (k<512) ; emb[x[4095]][k-512] (k>=512)
// ---------------------------------------------------------------------------
__global__ __launch_bounds__(256) void gemm_emb_kernel(
    const int* __restrict__ x, const float* __restrict__ emb,
    const float* __restrict__ W, const float* __restrict__ b_ih,
    const float* __restrict__ b_hh, float* __restrict__ xg)
{
    __shared__ float As[8][128];
    __shared__ float Bs[8][128];
    const int tid = threadIdx.x;
    const int bm = blockIdx.y * 128, bn = blockIdx.x * 128;
    const int tx = tid & 15, ty = tid >> 4;
    const int lrow = tid >> 1;
    const int lk4  = (tid & 1) * 4;
    const int lastTok = x[NSTEP];
    const int am = bm + lrow;
    const int tokRow = (am < NSTEP) ? x[am] : 0;
    const int bnrow = bn + lrow;

    float acc[8][8];
#pragma unroll
    for (int i = 0; i < 8; ++i)
#pragma unroll
        for (int j = 0; j < 8; ++j) acc[i][j] = 0.0f;

    for (int k0 = 0; k0 < KDIM; k0 += 8) {
        const int k = k0 + lk4;
        float4 av = make_float4(0.f, 0.f, 0.f, 0.f);
        if (am < NSTEP) {
            const int tok = (k < EDIM) ? tokRow : lastTok;
            const int kk  = (k < EDIM) ? k : (k - EDIM);
            av = *(const float4*)(emb + (size_t)tok * EDIM + kk);
        }
        const float4 bv = *(const float4*)(W + (size_t)bnrow * KDIM + k);
        __syncthreads();
        As[lk4 + 0][lrow] = av.x; As[lk4 + 1][lrow] = av.y;
        As[lk4 + 2][lrow] = av.z; As[lk4 + 3][lrow] = av.w;
        Bs[lk4 + 0][lrow] = bv.x; Bs[lk4 + 1][lrow] = bv.y;
        Bs[lk4 + 2][lrow] = bv.z; Bs[lk4 + 3][lrow] = bv.w;
        __syncthreads();
#pragma unroll
        for (int kk = 0; kk < 8; ++kk) {
            const float4 a0 = *(const float4*)&As[kk][ty * 4];
            const float4 a1 = *(const float4*)&As[kk][ty * 4 + 64];
            const float4 b0 = *(const float4*)&Bs[kk][tx * 4];
            const float4 b1 = *(const float4*)&Bs[kk][tx * 4 + 64];
            const float a[8] = {a0.x, a0.y, a0.z, a0.w, a1.x, a1.y, a1.z, a1.w};
            const float b[8] = {b0.x, b0.y, b0.z, b0.w, b1.x, b1.y, b1.z, b1.w};
#pragma unroll
            for (int i = 0; i < 8; ++i)
#pragma unroll
                for (int j = 0; j < 8; ++j) acc[i][j] += a[i] * b[j];
        }
    }
#pragma unroll
    for (int i = 0; i < 8; ++i) {
        const int m = bm + ((i < 4) ? (ty * 4 + i) : (64 + ty * 4 + i - 4));
        if (m >= NSTEP) continue;
#pragma unroll
        for (int j = 0; j < 8; ++j) {
            const int n = bn + ((j < 4) ? (tx * 4 + j) : (64 + tx * 4 + j - 4));
            xg[(size_t)m * GDIM + n] = acc[i][j] + b_ih[n] + b_hh[n];
        }
    }
}

// ---------------------------------------------------------------------------
// GEMM2: out[m][n] = sum_k hs[m][k]*W_out[n][k] + b_out[n]   (N=1221)
// ---------------------------------------------------------------------------
__global__ __launch_bounds__(256) void gemm_out_kernel(
    const float* __restrict__ A, const float* __restrict__ W,
    const float* __restrict__ bias, float* __restrict__ C)
{
    __shared__ float As[8][128];
    __shared__ float Bs[8][128];
    const int tid = threadIdx.x;
    const int bm = blockIdx.y * 128, bn = blockIdx.x * 128;
    const int tx = tid & 15, ty = tid >> 4;
    const int lrow = tid >> 1;
    const int lk4  = (tid & 1) * 4;
    const int am = bm + lrow;
    const int bnrow = bn + lrow;

    float acc[8][8];
#pragma unroll
    for (int i = 0; i < 8; ++i)
#pragma unroll
        for (int j = 0; j < 8; ++j) acc[i][j] = 0.0f;

    for (int k0 = 0; k0 < KDIM; k0 += 8) {
        const int k = k0 + lk4;
        float4 av = make_float4(0.f, 0.f, 0.f, 0.f);
        if (am < NSTEP) av = *(const float4*)(A + (size_t)am * KDIM + k);
        float4 bv = make_float4(0.f, 0.f, 0.f, 0.f);
        if (bnrow < CDIM) bv = *(const float4*)(W + (size_t)bnrow * KDIM + k);
        __syncthreads();
        As[lk4 + 0][lrow] = av.x; As[lk4 + 1][lrow] = av.y;
        As[lk4 + 2][lrow] = av.z; As[lk4 + 3][lrow] = av.w;
        Bs[lk4 + 0][lrow] = bv.x; Bs[lk4 + 1][lrow] = bv.y;
        Bs[lk4 + 2][lrow] = bv.z; Bs[lk4 + 3][lrow] = bv.w;
        __syncthreads();
#pragma unroll
        for (int kk = 0; kk < 8; ++kk) {
            const float4 a0 = *(const float4*)&As[kk][ty * 4];
            const float4 a1 = *(const float4*)&As[kk][ty * 4 + 64];
            const float4 b0 = *(const float4*)&Bs[kk][tx * 4];
            const float4 b1 = *(const float4*)&Bs[kk][tx * 4 + 64];
            const float a[8] = {a0.x, a0.y, a0.z, a0.w, a1.x, a1.y, a1.z, a1.w};
            const float b[8] = {b0.x, b0.y, b0.z, b0.w, b1.x, b1.y, b1.z, b1.w};
#pragma unroll
            for (int i = 0; i < 8; ++i)
#pragma unroll
                for (int j = 0; j < 8; ++j) acc[i][j] += a[i] * b[j];
        }
    }
#pragma unroll
    for (int i = 0; i < 8; ++i) {
        const int m = bm + ((i < 4) ? (ty * 4 + i) : (64 + ty * 4 + i - 4));
        if (m >= NSTEP) continue;
#pragma unroll
        for (int j = 0; j < 8; ++j) {
            const int n = bn + ((j < 4) ? (tx * 4 + j) : (64 + tx * 4 + j - 4));
            if (n < CDIM) C[(size_t)m * CDIM + n] = acc[i][j] + bias[n];
        }
    }
}

// ---------------------------------------------------------------------------
// Persistent LSTM scan, v6. 64 WGs x 256 threads; WG g owns hidden units
// g*16..g*16+15 (64 gate rows). 4 rows/thread for LDS reuse:
//   thread (u = tid&15, c = tid>>4) computes the 4 gate rows (i,f,g,o) of
//   unit u over column chunk c (64 cols). 256 weight floats pinned in VGPRs
//   (1 wave/SIMD). h chunk read once from LDS (16 x b128), reused 4x ->
//   delivered LDS bytes 64KB/step (4x less than v3).
// Handoff: tagged u64 hb[par][i]=(t<<32)|bits(h_i); batched 4-el poll per
// thread (poll == data load, no fences). Reduction: shfl_xor(16,32) then
// ds_add from 16 lanes; finalize on wave0 (64 lanes = 64 gate activations,
// intra-wave LDS regroup), cell state in lane registers (tid<16).
// 2 barriers/step. gate_acc needs no parity: finalize(t) completes before
// barrier1(t+1); any ds_add of step t+1 is after barrier1(t+1).
// hb reuse at t+2 is safe (2-step production slack, as before).
// ---------------------------------------------------------------------------
__global__ __launch_bounds__(256, 1) void scan_kernel(
    const float* __restrict__ xg, const float* __restrict__ Whh,
    float* __restrict__ hs, unsigned long long* hb)
{
    __shared__ float h_s[HDIM];
    __shared__ float gate_acc[64];   // [gate*16 + unit]
    __shared__ float act_s[64];
    const int g = blockIdx.x, tid = threadIdx.x;
    const int lane = tid & 63;
    const int u = tid & 15, c = tid >> 4;        // unit, col-chunk

    // weights: 4 gate rows of unit u, cols c*64 .. c*64+63  (64 float4)
    float4 w4[4][16];
#pragma unroll
    for (int q = 0; q < 4; ++q)
#pragma unroll
        for (int i = 0; i < 16; ++i)
            w4[q][i] = *(const float4*)(Whh + (size_t)(q * HDIM + g * UNITS + u) * KDIM
                                        + c * 64 + i * 4);
#pragma unroll
    for (int q = 0; q < 4; ++q)
#pragma unroll
        for (int i = 0; i < 16; ++i)
            asm volatile("" : "+v"(w4[q][i].x), "+v"(w4[q][i].y),
                              "+v"(w4[q][i].z), "+v"(w4[q][i].w));

    if (tid < 64) gate_acc[tid] = 0.0f;
    float creg = 0.0f;                            // cell state, lanes tid<16
    __syncthreads();

    for (int t = 1; t <= NSTEP; ++t) {
        // xg for this step: wave0's 64 lanes, one gate value each (issue early)
        float xgv = 0.0f;
        if (tid < 64)
            xgv = xg[(size_t)(t - 1) * GDIM + (tid >> 4) * HDIM + g * UNITS + (tid & 15)];

        if (t > 1) {
            const int sp = (t - 1) & 1;
            const unsigned long long* src = hb + sp * HDIM;
            const int want = t - 1;
            unsigned long long v[4];
            int need = 0xF;
            do {
#pragma unroll
                for (int k = 0; k < 4; ++k)
                    if (need & (1 << k))
                        v[k] = __hip_atomic_load(&src[tid + k * 256],
                                                 __ATOMIC_RELAXED,
                                                 __HIP_MEMORY_SCOPE_AGENT);
#pragma unroll
                for (int k = 0; k < 4; ++k)
                    if ((need & (1 << k)) && (int)(v[k] >> 32) == want)
                        need &= ~(1 << k);
            } while (need);
#pragma unroll
            for (int k = 0; k < 4; ++k)
                h_s[tid + k * 256] = __uint_as_float((unsigned)v[k]);
        }
        __syncthreads();   // (1) h_s ready

        if (t > 1) {
            float acc0 = 0.f, acc1 = 0.f, acc2 = 0.f, acc3 = 0.f;
#pragma unroll
            for (int i = 0; i < 16; ++i) {
                const float4 h4 = *(const float4*)&h_s[c * 64 + i * 4];
                acc0 += w4[0][i].x * h4.x + w4[0][i].y * h4.y + w4[0][i].z * h4.z + w4[0][i].w * h4.w;
                acc1 += w4[1][i].x * h4.x + w4[1][i].y * h4.y + w4[1][i].z * h4.z + w4[1][i].w * h4.w;
                acc2 += w4[2][i].x * h4.x + w4[2][i].y * h4.y + w4[2][i].z * h4.z + w4[2][i].w * h4.w;
                acc3 += w4[3][i].x * h4.x + w4[3][i].y * h4.y + w4[3][i].z * h4.z + w4[3][i].w * h4.w;
            }
            // reduce over chunk groups within wave: lanes u,16+u,32+u,48+u
            acc0 += __shfl_xor(acc0, 16, 64); acc0 += __shfl_xor(acc0, 32, 64);
            acc1 += __shfl_xor(acc1, 16, 64); acc1 += __shfl_xor(acc1, 32, 64);
            acc2 += __shfl_xor(acc2, 16, 64); acc2 += __shfl_xor(acc2, 32, 64);
            acc3 += __shfl_xor(acc3, 16, 64); acc3 += __shfl_xor(acc3, 32, 64);
            if (lane < 16) {                      // one lane per (wave, unit)
                atomicAdd(&gate_acc[u], acc0);
                atomicAdd(&gate_acc[16 + u], acc1);
                atomicAdd(&gate_acc[32 + u], acc2);
                atomicAdd(&gate_acc[48 + u], acc3);
            }
        }
        __syncthreads();   // (2) all partials accumulated

        if (tid < 64) {
            const float gv = gate_acc[tid] + xgv;
            gate_acc[tid] = 0.0f;                 // re-arm for next step
            act_s[tid] = (tid >= 32 && tid < 48) ? tanhf_(gv) : sigmoidf_(gv);
            // intra-wave LDS: DS pipe is in-order; reads below see the writes
            if (tid < 16) {
                const float ig = act_s[tid];
                const float fg = act_s[16 + tid];
                const float gG = act_s[32 + tid];
                const float og = act_s[48 + tid];
                const float cc = fg * creg + ig * gG;
                creg = cc;
                const float h = og * tanhf_(cc);
                const unsigned long long pv =
                    ((unsigned long long)(unsigned)t << 32) | __float_as_uint(h);
                __hip_atomic_store(&hb[(t & 1) * HDIM + g * UNITS + tid], pv,
                                   __ATOMIC_RELAXED, __HIP_MEMORY_SCOPE_AGENT);
                hs[(size_t)(t - 1) * HDIM + g * UNITS + tid] = h;
            }
        }
        // no trailing barrier: h_s writes of t+1 are gated by poll(t+1), which
        // needs every WG's post of t, which follows each WG's barrier (2).
    }
}

extern "C" void kernel_launch(void* const* d_in, const int* in_sizes, int n_in,
                              void* d_out, int out_size, void* d_ws, size_t ws_size,
                              hipStream_t stream)
{
    const int*   x     = (const int*)d_in[0];
    const float* emb   = (const float*)d_in[1];
    const float* W_ih  = (const float*)d_in[2];
    const float* W_hh  = (const float*)d_in[3];
    const float* b_ih  = (const float*)d_in[4];
    const float* b_hh  = (const float*)d_in[5];
    const float* W_out = (const float*)d_in[6];
    const float* b_out = (const float*)d_in[7];
    float* out = (float*)d_out;

    float* xg = (float*)d_ws;                          // 4095*4096 f32
    float* hs = xg + (size_t)NSTEP * GDIM;             // 4095*1024 f32
    unsigned long long* hb =
        (unsigned long long*)(hs + (size_t)NSTEP * HDIM);  // 2*1024 u64 (8B aligned)

    dim3 blk(256);
    dim3 g1(GDIM / 128, 32);                           // 32 x 32
    gemm_emb_kernel<<<g1, blk, 0, stream>>>(x, emb, W_ih, b_ih, b_hh, xg);

    scan_kernel<<<dim3(SNWG), blk, 0, stream>>>(xg, W_hh, hs, hb);

    dim3 g2((CDIM + 127) / 128, 32);                   // 10 x 32
    gemm_out_kernel<<<g2, blk, 0, stream>>>(hs, W_out, b_out, out);
}